// Round 3
// baseline (1319.274 us; speedup 1.0000x reference)
//
#include <hip/hip_runtime.h>
#include <hip/hip_bf16.h>
#include <math.h>

#define B_ 16
#define L_ 4096
#define D_ 512
#define H_ 512

typedef short bf16x8 __attribute__((ext_vector_type(8)));
typedef float f32x4 __attribute__((ext_vector_type(4)));

__device__ __forceinline__ unsigned short f2bf(float f) {
    unsigned int u = __float_as_uint(f);
    u = (u + 0x7FFFu + ((u >> 16) & 1u)) >> 16;
    return (unsigned short)u;
}
__device__ __forceinline__ float bf2f(unsigned short h) {
    return __uint_as_float(((unsigned int)h) << 16);
}

// ---------------------------------------------------------------------------
__global__ __launch_bounds__(256) void cvt_x(const float* __restrict__ in,
                                             unsigned short* __restrict__ out, int n) {
    int i = (blockIdx.x * blockDim.x + threadIdx.x) * 4;
    int stride = gridDim.x * blockDim.x * 4;
    for (; i < n; i += stride) {
        float4 v = *(const float4*)(in + i);
        ushort4 o;
        o.x = f2bf(v.x); o.y = f2bf(v.y); o.z = f2bf(v.z); o.w = f2bf(v.w);
        *(ushort4*)(out + i) = o;
    }
}

// W (K x N fp32, row-major) -> Wt (N x K bf16, row-major)
__global__ __launch_bounds__(256) void transcvt(const float* __restrict__ W,
                                                unsigned short* __restrict__ Wt,
                                                int K, int N) {
    int idx = blockIdx.x * 256 + threadIdx.x;
    int total = K * N;
    int stride = gridDim.x * 256;
    for (; idx < total; idx += stride) {
        int n = idx / K;
        int k = idx - n * K;
        Wt[idx] = f2bf(W[(size_t)k * N + n]);
    }
}

__global__ __launch_bounds__(256) void fill_k(float* p, float v, int n) {
    int i = blockIdx.x * 256 + threadIdx.x;
    int stride = gridDim.x * 256;
    for (; i < n; i += stride) p[i] = v;
}

// ---------------------------------------------------------------------------
// bf16 MFMA GEMM: C = A (MxK) * Bt^T (Bt is NxK), 128x128 tile, 4 waves.
// EPI 0: SRU projection -> planar z/f/r bf16 (o0,o1,o2; bias1=b_f, bias2=b_r)
// EPI 1: GELU(v + bias1) -> bf16 o0 (row-major MxN)
// EPI 2: oF[row*512+col] += v + bias1[col]   (residual fused, N==512)
// ---------------------------------------------------------------------------
template <int EPI>
__global__ __launch_bounds__(256) void gemm_bf16(
    const unsigned short* __restrict__ A,
    const unsigned short* __restrict__ Bt,
    int M, int N, int K,
    unsigned short* __restrict__ o0,
    unsigned short* __restrict__ o1,
    unsigned short* __restrict__ o2,
    float* __restrict__ oF,
    const float* __restrict__ bias1,
    const float* __restrict__ bias2)
{
    __shared__ unsigned short As[128 * 40];  // padded stride 40 bf16 (80B)
    __shared__ unsigned short Bs[128 * 40];

    const int tid  = threadIdx.x;
    const int bm   = blockIdx.x, bn = blockIdx.y;
    const int wave = tid >> 6, lane = tid & 63;
    const int wm   = (wave >> 1) * 64, wn = (wave & 1) * 64;
    const int lrow = lane & 15;
    const int kb   = (lane >> 4) * 8;

    f32x4 acc[4][4];
#pragma unroll
    for (int i = 0; i < 4; i++)
#pragma unroll
        for (int j = 0; j < 4; j++) acc[i][j] = (f32x4){0.f, 0.f, 0.f, 0.f};

    const int r0  = tid >> 2;          // staging row 0..63 (and +64)
    const int kc0 = (tid & 3) * 8;     // staging k-element offset {0,8,16,24}

    for (int k0 = 0; k0 < K; k0 += 32) {
        __syncthreads();
        {
            const unsigned short* ga  = A  + (size_t)(bm * 128 + r0) * K + k0 + kc0;
            const unsigned short* ga2 = A  + (size_t)(bm * 128 + r0 + 64) * K + k0 + kc0;
            const unsigned short* gb  = Bt + (size_t)(bn * 128 + r0) * K + k0 + kc0;
            const unsigned short* gb2 = Bt + (size_t)(bn * 128 + r0 + 64) * K + k0 + kc0;
            *(int4*)(&As[r0 * 40 + kc0])        = *(const int4*)ga;
            *(int4*)(&As[(r0 + 64) * 40 + kc0]) = *(const int4*)ga2;
            *(int4*)(&Bs[r0 * 40 + kc0])        = *(const int4*)gb;
            *(int4*)(&Bs[(r0 + 64) * 40 + kc0]) = *(const int4*)gb2;
        }
        __syncthreads();

        bf16x8 af[4], bfv[4];
#pragma unroll
        for (int mt = 0; mt < 4; mt++)
            af[mt] = *(const bf16x8*)(&As[(wm + mt * 16 + lrow) * 40 + kb]);
#pragma unroll
        for (int nt = 0; nt < 4; nt++)
            bfv[nt] = *(const bf16x8*)(&Bs[(wn + nt * 16 + lrow) * 40 + kb]);
#pragma unroll
        for (int mt = 0; mt < 4; mt++)
#pragma unroll
            for (int nt = 0; nt < 4; nt++)
                acc[mt][nt] = __builtin_amdgcn_mfma_f32_16x16x32_bf16(
                    af[mt], bfv[nt], acc[mt][nt], 0, 0, 0);
    }

    // epilogue: D[row][col], col = lane&15, row = (lane>>4)*4 + j  [m89-verified]
    const int rgrp = (lane >> 4) * 4;
#pragma unroll
    for (int mt = 0; mt < 4; mt++) {
#pragma unroll
        for (int nt = 0; nt < 4; nt++) {
            const int col  = bn * 128 + wn + nt * 16 + lrow;
            const int row0 = bm * 128 + wm + mt * 16 + rgrp;
#pragma unroll
            for (int j = 0; j < 4; j++) {
                const int row = row0 + j;
                float v = acc[mt][nt][j];
                if (EPI == 0) {
                    const int plane = col >> 9;
                    const int hh    = col & 511;
                    const size_t idx = (size_t)row * 512 + hh;
                    if (plane == 0) {
                        o0[idx] = f2bf(v);
                    } else if (plane == 1) {
                        o1[idx] = f2bf(1.0f / (1.0f + expf(-(v + bias1[hh]))));
                    } else {
                        o2[idx] = f2bf(1.0f / (1.0f + expf(-(v + bias2[hh]))));
                    }
                } else if (EPI == 1) {
                    float t = v + bias1[col];
                    float gl = 0.5f * t * (1.0f + erff(t * 0.70710678118654752f));
                    o0[(size_t)row * N + col] = f2bf(gl);
                } else {
                    const size_t idx = (size_t)row * 512 + col;
                    oF[idx] += v + bias1[col];
                }
            }
        }
    }
}

// ---------------------------------------------------------------------------
// SRU scan, 3-pass chunked linear recurrence. c_t = f*c + (1-f)*z
// planar [b][l][h] within the group slab; chunk = 128 timesteps, 32 chunks.
// ---------------------------------------------------------------------------
#define CHUNK 128
#define NCH   32

__global__ __launch_bounds__(256) void scan_a(const unsigned short* __restrict__ fP,
                                              const unsigned short* __restrict__ zP,
                                              float* __restrict__ Pw,
                                              float* __restrict__ C0w) {
    int idx = blockIdx.x * 256 + threadIdx.x;       // (b_local, ch, h)
    int h  = idx & 511;
    int ch = (idx >> 9) & (NCH - 1);
    int b  = idx >> 14;
    size_t base = ((size_t)b * L_ + (size_t)ch * CHUNK) * H_ + h;
    float c = 0.f, Pp = 1.f;
#pragma unroll 8
    for (int t = 0; t < CHUNK; t++) {
        float f = bf2f(fP[base]);
        float z = bf2f(zP[base]);
        c  = f * c + (1.f - f) * z;
        Pp *= f;
        base += H_;
    }
    Pw[idx]  = Pp;
    C0w[idx] = c;
}

__global__ __launch_bounds__(256) void scan_b(const float* __restrict__ Pw,
                                              const float* __restrict__ C0w,
                                              float* __restrict__ cin) {
    int idx = blockIdx.x * 256 + threadIdx.x;       // (b_local, h)
    int h = idx & 511;
    int b = idx >> 9;
    float c = 0.f;
#pragma unroll
    for (int ch = 0; ch < NCH; ch++) {
        int w = ((b * NCH) + ch) * 512 + h;
        cin[w] = c;
        c = Pw[w] * c + C0w[w];
    }
}

__global__ __launch_bounds__(256) void scan_c(const unsigned short* __restrict__ fP,
                                              const unsigned short* __restrict__ zP,
                                              const unsigned short* __restrict__ rP,
                                              const float* __restrict__ x,
                                              const float* __restrict__ cin,
                                              float* __restrict__ x1) {
    int idx = blockIdx.x * 256 + threadIdx.x;
    int h  = idx & 511;
    int ch = (idx >> 9) & (NCH - 1);
    int b  = idx >> 14;
    size_t base = ((size_t)b * L_ + (size_t)ch * CHUNK) * H_ + h;
    float c = cin[idx];
#pragma unroll 4
    for (int t = 0; t < CHUNK; t++) {
        float f = bf2f(fP[base]);
        float z = bf2f(zP[base]);
        c = f * c + (1.f - f) * z;
        float r  = bf2f(rP[base]);
        float xv = x[base];
        x1[base] = (2.f - r) * xv + r * c;   // x + r*c + (1-r)*x
        base += H_;
    }
}

// ---------------------------------------------------------------------------
// LayerNorm over 512, one wave per row (8 floats/lane).
// MODE 0: fp32 out only. MODE 1: bf16 out only. MODE 2: both (fp32 + bf16).
// ---------------------------------------------------------------------------
template <int MODE>
__global__ __launch_bounds__(256) void ln_k(const float* __restrict__ in,
                                            const float* __restrict__ g,
                                            const float* __restrict__ b,
                                            float* __restrict__ outF,
                                            unsigned short* __restrict__ outB,
                                            int nrows) {
    int gw = blockIdx.x * 4 + (threadIdx.x >> 6);
    if (gw >= nrows) return;
    int lane = threadIdx.x & 63;
    const float* row = in + (size_t)gw * 512 + lane * 8;
    float4 a = *(const float4*)row;
    float4 c = *(const float4*)(row + 4);
    float xv[8] = {a.x, a.y, a.z, a.w, c.x, c.y, c.z, c.w};
    float s = 0.f, s2 = 0.f;
#pragma unroll
    for (int j = 0; j < 8; j++) { s += xv[j]; s2 += xv[j] * xv[j]; }
#pragma unroll
    for (int o = 32; o; o >>= 1) {
        s  += __shfl_xor(s, o, 64);
        s2 += __shfl_xor(s2, o, 64);
    }
    float m    = s * (1.f / 512.f);
    float var  = s2 * (1.f / 512.f) - m * m;
    float rstd = rsqrtf(var + 1e-5f);
#pragma unroll
    for (int j = 0; j < 8; j++) {
        int col = lane * 8 + j;
        float y = (xv[j] - m) * rstd * g[col] + b[col];
        if (MODE == 0 || MODE == 2)
            outF[(size_t)gw * 512 + col] = y;
        if (MODE == 1 || MODE == 2)
            outB[(size_t)gw * 512 + col] = f2bf(y);
    }
}

// ---------------------------------------------------------------------------
extern "C" void kernel_launch(void* const* d_in, const int* in_sizes, int n_in,
                              void* d_out, int out_size, void* d_ws, size_t ws_size,
                              hipStream_t stream) {
    const float* x     = (const float*)d_in[0];
    const float* W_sru = (const float*)d_in[1];
    const float* b_f   = (const float*)d_in[2];
    const float* b_r   = (const float*)d_in[3];
    const float* ln1_g = (const float*)d_in[4];
    const float* ln1_b = (const float*)d_in[5];
    const float* W1    = (const float*)d_in[6];
    const float* b1    = (const float*)d_in[7];
    const float* W2    = (const float*)d_in[8];
    const float* b2    = (const float*)d_in[9];
    const float* ln2_g = (const float*)d_in[10];
    const float* ln2_b = (const float*)d_in[11];
    float* out = (float*)d_out;

    // ---- adaptive batch grouping: largest g with footprint <= ws_size ----
    const size_t W_BYTES = 5767168;          // wsrut + w1t + w2t (aligned)
    const size_t PER_G   = 46333952;         // per-batch buffer bytes
    int g = 0;
    const int cands[5] = {16, 8, 4, 2, 1};
    for (int ci = 0; ci < 5; ci++) {
        if (W_BYTES + (size_t)cands[ci] * PER_G <= ws_size) { g = cands[ci]; break; }
    }
    if (g == 0) {
        float enc = -(100000.0f + (float)(ws_size >> 20));
        fill_k<<<dim3(2048), dim3(256), 0, stream>>>(out, enc, out_size);
        return;
    }

    const int Mg = g * L_;                   // rows per group
    char* ws = (char*)d_ws;
    size_t off = 0;
    auto alloc = [&](size_t bytes) { char* p = ws + off; off = (off + bytes + 255) & ~(size_t)255; return p; };
    unsigned short* wsrut = (unsigned short*)alloc(1536 * 512 * 2);
    unsigned short* w1t   = (unsigned short*)alloc(2048 * 512 * 2);
    unsigned short* w2t   = (unsigned short*)alloc(512 * 2048 * 2);
    unsigned short* xb    = (unsigned short*)alloc((size_t)Mg * 512 * 2);
    unsigned short* zP    = (unsigned short*)alloc((size_t)Mg * 512 * 2);
    unsigned short* fP    = (unsigned short*)alloc((size_t)Mg * 512 * 2);
    unsigned short* rP    = (unsigned short*)alloc((size_t)Mg * 512 * 2);
    float*          x1    = (float*)alloc((size_t)Mg * 512 * 4);
    unsigned short* xln   = (unsigned short*)alloc((size_t)Mg * 512 * 2);
    unsigned short* hbuf  = (unsigned short*)alloc((size_t)Mg * 2048 * 2);
    float*          Pw    = (float*)alloc((size_t)g * NCH * 512 * 4);
    float*          C0w   = (float*)alloc((size_t)g * NCH * 512 * 4);
    float*          cinw  = (float*)alloc((size_t)g * NCH * 512 * 4);

    // weight transposes (once)
    transcvt<<<dim3(768), dim3(256), 0, stream>>>(W_sru, wsrut, 512, 1536);
    transcvt<<<dim3(1024), dim3(256), 0, stream>>>(W1, w1t, 512, 2048);
    transcvt<<<dim3(1024), dim3(256), 0, stream>>>(W2, w2t, 2048, 512);

    const int ngrp = 16 / g;
    for (int grp = 0; grp < ngrp; ++grp) {
        const size_t roff = (size_t)grp * Mg * 512;   // element offset into x / out
        const float* xg = x + roff;
        float* outg = out + roff;

        // 0) x -> bf16
        cvt_x<<<dim3(2048), dim3(256), 0, stream>>>(xg, xb, Mg * 512);

        // 1) SRU projection GEMM + gate epilogue -> z/f/r planes
        gemm_bf16<0><<<dim3(Mg / 128, 12), dim3(256), 0, stream>>>(
            xb, wsrut, Mg, 1536, 512, zP, fP, rP, (float*)nullptr, b_f, b_r);

        // 2) chunked scan + highway + residual -> x1 (fp32)
        scan_a<<<dim3(g * 64), dim3(256), 0, stream>>>(fP, zP, Pw, C0w);
        scan_b<<<dim3(g * 2), dim3(256), 0, stream>>>(Pw, C0w, cinw);
        scan_c<<<dim3(g * 64), dim3(256), 0, stream>>>(fP, zP, rP, xg, cinw, x1);

        // 3) LN1 -> x1 (fp32, residual base = LN1 OUTPUT) and xln (bf16 GEMM input)
        ln_k<2><<<dim3(Mg / 4), dim3(256), 0, stream>>>(
            x1, ln1_g, ln1_b, x1, xln, Mg);

        // 4) FFN; FFN2 adds bias+residual in-place into x1 (now LN1 output)
        gemm_bf16<1><<<dim3(Mg / 128, 16), dim3(256), 0, stream>>>(
            xln, w1t, Mg, 2048, 512,
            hbuf, (unsigned short*)nullptr, (unsigned short*)nullptr,
            (float*)nullptr, b1, (const float*)nullptr);
        gemm_bf16<2><<<dim3(Mg / 128, 4), dim3(256), 0, stream>>>(
            hbuf, w2t, Mg, 512, 2048,
            (unsigned short*)nullptr, (unsigned short*)nullptr, (unsigned short*)nullptr,
            x1, b2, (const float*)nullptr);

        // 5) LN2 -> out (fp32)
        ln_k<0><<<dim3(Mg / 4), dim3(256), 0, stream>>>(
            x1, ln2_g, ln2_b, outg, (unsigned short*)nullptr, Mg);
    }
}